// Round 1
// baseline (500.262 us; speedup 1.0000x reference)
//
#include <hip/hip_runtime.h>

#define N_NODES 50000
#define DEG 16
#define N_EDGES 800000
#define IND 128
#define EDIM 64

typedef __bf16 bf16x8 __attribute__((ext_vector_type(8)));
typedef float  f32x4  __attribute__((ext_vector_type(4)));

__device__ __forceinline__ unsigned short f2bfu(float f) {
  __bf16 b = (__bf16)f;
  return __builtin_bit_cast(unsigned short, b);
}
__device__ __forceinline__ float bfu2f(unsigned short u) {
  __bf16 b = __builtin_bit_cast(__bf16, u);
  return (float)b;
}
__device__ __forceinline__ f32x4 mfma16(bf16x8 a, bf16x8 b, f32x4 c) {
  return __builtin_amdgcn_mfma_f32_16x16x32_bf16(a, b, c, 0, 0, 0);
}
__device__ __forceinline__ bf16x8 pack8(float4 a, float4 b) {
  bf16x8 r;
  r[0]=(__bf16)a.x; r[1]=(__bf16)a.y; r[2]=(__bf16)a.z; r[3]=(__bf16)a.w;
  r[4]=(__bf16)b.x; r[5]=(__bf16)b.y; r[6]=(__bf16)b.z; r[7]=(__bf16)b.w;
  return r;
}

// ---------------- P0: pack weights into MFMA B-fragment order (bf16) -------
// WpreF: [kb(4)][ct(16)][lane(64)][j(8)]  B[k][col], col<128 -> Wa, col>=128 -> Wb
// WcF:   [kb(2)][ct(8)][lane][j]          Wc rows 256..319 of W_pre
// WfoldF:[kb(20)][ct(8)][lane][j]         k<128: Wp0 ; k>=128: Wp1+Wp2+Wp3, agg rows
//                                         permuted to interleaved (c,type) order
__global__ __launch_bounds__(256) void pack_weights(const float* W_pre, const float* W_post,
                                                    unsigned short* WpreF, unsigned short* WcF,
                                                    unsigned short* WfoldF) {
  int idx = blockIdx.x * 256 + threadIdx.x;
  if (idx < 32768) {
    int j = idx & 7, lane = (idx >> 3) & 63, ct = (idx >> 9) & 15, kb = idx >> 13;
    int k = kb * 32 + (lane >> 4) * 8 + j;
    int col = ct * 16 + (lane & 15);
    float v = (col < 128) ? W_pre[k * 128 + col] : W_pre[(128 + k) * 128 + (col - 128)];
    WpreF[idx] = f2bfu(v);
  } else if (idx < 32768 + 8192) {
    int i = idx - 32768;
    int j = i & 7, lane = (i >> 3) & 63, ct = (i >> 9) & 7, kb = i >> 12;
    int k = kb * 32 + (lane >> 4) * 8 + j;
    int col = ct * 16 + (lane & 15);
    WcF[i] = f2bfu(W_pre[(256 + k) * 128 + col]);
  } else if (idx < 122880) {
    int i = idx - 40960;
    int j = i & 7, lane = (i >> 3) & 63, ct = (i >> 9) & 7, kb = i >> 12; // kb 0..19
    int k = kb * 32 + (lane >> 4) * 8 + j;
    int col = ct * 16 + (lane & 15);
    float v;
    if (k < 128) {
      v = W_post[k * 128 + col];
    } else {
      int f = k - 128, c = f >> 2, t = f & 3;
      int r0 = 128 + t * 128 + c;
      v = W_post[(size_t)r0 * 128 + col] + W_post[(size_t)(r0 + 512) * 128 + col] +
          W_post[(size_t)(r0 + 1024) * 128 + col];
    }
    WfoldF[i] = f2bfu(v);
  }
}

// ---------------- P1: cast h -> bf16 into Abuf cols 0..127 (row stride 640) --
__global__ __launch_bounds__(256) void cast_h(const float* h, unsigned short* Abuf) {
  int tid = blockIdx.x * 256 + threadIdx.x;   // exactly N*32 threads
  int n = tid >> 5, g = tid & 31;
  float4 v = *(const float4*)(h + (size_t)n * 128 + g * 4);
  unsigned int lo = (unsigned int)f2bfu(v.x) | ((unsigned int)f2bfu(v.y) << 16);
  unsigned int hi = (unsigned int)f2bfu(v.z) | ((unsigned int)f2bfu(v.w) << 16);
  uint2 u; u.x = lo; u.y = hi;
  *(uint2*)(Abuf + (size_t)n * 640 + g * 4) = u;
}

// ---------------- P2: ha = h@Wa (bf16), hb = h@Wb + b_pre (f32) -------------
// one wave = 16 node rows, K=128, Ncols=256 (ha | hb)
__global__ __launch_bounds__(256) void pre_gemm(const unsigned short* Abuf,
                                                const unsigned short* WpreF,
                                                const float* b_pre,
                                                unsigned short* haB, float* hbF) {
  int lane = threadIdx.x & 63;
  int gw = blockIdx.x * 4 + (threadIdx.x >> 6);
  size_t base = (size_t)gw * 16;
  if (base >= N_NODES) return;
  int q = lane >> 4, c16 = lane & 15;
  f32x4 acc[16];
#pragma unroll
  for (int i = 0; i < 16; i++) acc[i] = (f32x4){0.f, 0.f, 0.f, 0.f};
#pragma unroll
  for (int kb = 0; kb < 4; kb++) {
    bf16x8 a = *(const bf16x8*)(Abuf + (base + c16) * 640 + kb * 32 + q * 8);
#pragma unroll
    for (int ct = 0; ct < 16; ct++) {
      bf16x8 b = *(const bf16x8*)(WpreF + ((size_t)(kb * 16 + ct) * 64 + lane) * 8);
      acc[ct] = mfma16(a, b, acc[ct]);
    }
  }
#pragma unroll
  for (int ct = 0; ct < 8; ct++) {
    int col = ct * 16 + c16;
#pragma unroll
    for (int r = 0; r < 4; r++) {
      size_t row = base + q * 4 + r;
      haB[row * 128 + col] = f2bfu(acc[ct][r]);
    }
  }
#pragma unroll
  for (int ct = 8; ct < 16; ct++) {
    int col = (ct - 8) * 16 + c16;
    float bp = b_pre[col];
#pragma unroll
    for (int r = 0; r < 4; r++) {
      size_t row = base + q * 4 + r;
      hbF[row * 128 + col] = acc[ct][r] + bp;
    }
  }
}

// ---------------- A: fused edge pretrans + 4-aggregator reduce --------------
// one wave per node (loop of 8 nodes/wave): e[16 edges,128] = ef@Wc + ha[src] + hb[n]
// then sum/sumsq/max/min over the 16 rows -> agg written bf16 into Abuf cols 128..639
// interleaved as feature f = c*4 + type (type: 0=mean 1=max 2=min 3=std)
__global__ __launch_bounds__(256) void edge_agg(const float* ef, const int* src,
                                                const unsigned short* haB, const float* hbF,
                                                const unsigned short* WcF,
                                                unsigned short* Abuf) {
  __shared__ unsigned short lds[4][16 * 136];   // padded stride 136 shorts
  int lane = threadIdx.x & 63, wib = threadIdx.x >> 6;
  int q = lane >> 4, c16 = lane & 15;
  int gw = blockIdx.x * 4 + wib;
  unsigned short* myl = lds[wib];
  bf16x8 bw[16];
#pragma unroll
  for (int i = 0; i < 16; i++) bw[i] = *(const bf16x8*)(WcF + ((size_t)i * 64 + lane) * 8);
  int grow = lane >> 2, gchunk = lane & 3;
  for (int t = 0; t < 8; t++) {
    int n = gw * 8 + t;
    if (n >= N_NODES) return;
    size_t eb = (size_t)n * 16;
    int s = src[eb + c16];
    int srow = __shfl(s, grow, 64);
    // gather 16 ha rows (bf16, 256B each) into this wave's LDS scratch
    const int4* gp = (const int4*)(haB + (size_t)srow * 128 + gchunk * 32);
    int4 w0 = gp[0], w1 = gp[1], w2 = gp[2], w3 = gp[3];
    int4* lp = (int4*)(myl + grow * 136 + gchunk * 32);
    lp[0] = w0; lp[1] = w1; lp[2] = w2; lp[3] = w3;
    // ef tile -> two A fragments (K=64)
    const float4* ep = (const float4*)(ef + (eb + c16) * 64 + q * 8);
    float4 e0 = ep[0], e1 = ep[1];
    const float4* ep2 = (const float4*)(ef + (eb + c16) * 64 + 32 + q * 8);
    float4 e2 = ep2[0], e3 = ep2[1];
    bf16x8 a0 = pack8(e0, e1), a1 = pack8(e2, e3);
    f32x4 acc[8];
#pragma unroll
    for (int ct = 0; ct < 8; ct++) {
      acc[ct] = mfma16(a0, bw[ct], (f32x4){0.f, 0.f, 0.f, 0.f});
      acc[ct] = mfma16(a1, bw[8 + ct], acc[ct]);
    }
#pragma unroll
    for (int ct = 0; ct < 8; ct++) {
      int col = ct * 16 + c16;
      float hbc = hbF[(size_t)n * 128 + col];
      float sum = 0.f, s2 = 0.f, mx = -3.4e38f, mn = 3.4e38f;
#pragma unroll
      for (int r = 0; r < 4; r++) {
        int rr = q * 4 + r;
        float hav = bfu2f(myl[rr * 136 + col]);
        float e = acc[ct][r] + hbc + hav;
        sum += e; s2 += e * e; mx = fmaxf(mx, e); mn = fminf(mn, e);
      }
      for (int off = 16; off < 64; off <<= 1) {
        sum += __shfl_xor(sum, off, 64);
        s2  += __shfl_xor(s2,  off, 64);
        mx = fmaxf(mx, __shfl_xor(mx, off, 64));
        mn = fminf(mn, __shfl_xor(mn, off, 64));
      }
      float mean = sum * 0.0625f;
      float var = fmaxf(s2 * 0.0625f - mean * mean, 0.f);
      float sd = sqrtf(var + 1e-5f);
      float outv = (q == 0) ? mean : (q == 1) ? mx : (q == 2) ? mn : sd;
      Abuf[(size_t)n * 640 + 128 + col * 4 + q] = f2bfu(outv);
    }
  }
}

// ---------------- B: posttrans GEMM out = [h|agg]@Wfold + b_post ------------
// one wave = 32 rows x 128 cols, K=640
__global__ __launch_bounds__(256) void post_gemm(const unsigned short* Abuf,
                                                 const unsigned short* WfoldF,
                                                 const float* b_post, float* out) {
  int lane = threadIdx.x & 63;
  int gw = blockIdx.x * 4 + (threadIdx.x >> 6);
  size_t base = (size_t)gw * 32;
  if (base >= N_NODES) return;
  int q = lane >> 4, c16 = lane & 15;
  size_t r0 = base + c16;
  size_t r1 = base + 16 + c16;
  if (r1 > N_NODES - 1) r1 = N_NODES - 1;
  f32x4 acc[2][8];
#pragma unroll
  for (int i = 0; i < 2; i++)
#pragma unroll
    for (int j = 0; j < 8; j++) acc[i][j] = (f32x4){0.f, 0.f, 0.f, 0.f};
  for (int kb = 0; kb < 20; kb++) {
    bf16x8 a0 = *(const bf16x8*)(Abuf + r0 * 640 + kb * 32 + q * 8);
    bf16x8 a1 = *(const bf16x8*)(Abuf + r1 * 640 + kb * 32 + q * 8);
#pragma unroll
    for (int ct = 0; ct < 8; ct++) {
      bf16x8 b = *(const bf16x8*)(WfoldF + ((size_t)(kb * 8 + ct) * 64 + lane) * 8);
      acc[0][ct] = mfma16(a0, b, acc[0][ct]);
      acc[1][ct] = mfma16(a1, b, acc[1][ct]);
    }
  }
#pragma unroll
  for (int rt = 0; rt < 2; rt++)
#pragma unroll
    for (int ct = 0; ct < 8; ct++) {
      int col = ct * 16 + c16;
      float bp = b_post[col];
#pragma unroll
      for (int r = 0; r < 4; r++) {
        size_t row = base + rt * 16 + q * 4 + r;
        if (row < N_NODES) out[row * 128 + col] = acc[rt][ct][r] + bp;
      }
    }
}

extern "C" void kernel_launch(void* const* d_in, const int* in_sizes, int n_in,
                              void* d_out, int out_size, void* d_ws, size_t ws_size,
                              hipStream_t stream) {
  const float* h      = (const float*)d_in[0];
  const float* ef     = (const float*)d_in[1];
  const int*   src    = (const int*)d_in[2];
  // d_in[3] = dst: structure (sorted, deg=16) is exploited; amp=att=1 folded into WfoldF
  const float* W_pre  = (const float*)d_in[4];
  const float* b_pre  = (const float*)d_in[5];
  const float* W_post = (const float*)d_in[6];
  const float* b_post = (const float*)d_in[7];
  float* out = (float*)d_out;

  char* ws = (char*)d_ws;
  unsigned short* Abuf   = (unsigned short*)ws;                       // N*640 bf16 (64 MB)
  unsigned short* haB    = Abuf + (size_t)N_NODES * 640;              // N*128 bf16
  float*          hbF    = (float*)(haB + (size_t)N_NODES * 128);     // N*128 f32
  unsigned short* WpreF  = (unsigned short*)(hbF + (size_t)N_NODES * 128); // 32768
  unsigned short* WcF    = WpreF + 32768;                             // 8192
  unsigned short* WfoldF = WcF + 8192;                                // 81920
  (void)in_sizes; (void)n_in; (void)out_size; (void)ws_size;

  pack_weights<<<480, 256, 0, stream>>>(W_pre, W_post, WpreF, WcF, WfoldF);
  cast_h<<<6250, 256, 0, stream>>>(h, Abuf);
  pre_gemm<<<782, 256, 0, stream>>>(Abuf, WpreF, b_pre, haB, hbF);
  edge_agg<<<1563, 256, 0, stream>>>(ef, src, haB, hbF, WcF, Abuf);
  post_gemm<<<391, 256, 0, stream>>>(Abuf, WfoldF, b_post, out);
}